// Round 2
// baseline (351.816 us; speedup 1.0000x reference)
//
#include <hip/hip_runtime.h>

#define NN 50000
#define NPGc 100
#define NG 500
#define DEG 32
#define HC 128
#define HID 64

__device__ __forceinline__ float lrelu(float x) { return x > 0.0f ? x : 0.2f * x; }

// ---- prep: Wext[K][132] = [ W | W@as_h0 | W@as_h1 | W@ad_h0 | W@ad_h1 ] ----
__global__ void k_prep(const float* __restrict__ W, const float* __restrict__ as_,
                       const float* __restrict__ ad_, float* __restrict__ Wext, int K) {
  int t = threadIdx.x;
  for (int u = t; u < K * 128; u += blockDim.x) {
    int k = u >> 7, c = u & 127;
    Wext[k * 132 + c] = W[u];
  }
  for (int u = t; u < K * 4; u += blockDim.x) {
    int k = u >> 2, s = u & 3;
    const float* a = (s < 2) ? as_ : ad_;
    int h = s & 1;
    float acc = 0.f;
    for (int c = 0; c < 64; ++c) acc += W[k * 128 + h * 64 + c] * a[h * 64 + c];
    Wext[k * 132 + 128 + s] = acc;
  }
}

// ---- in-GEMM: xp[N,128] = in(@BN?)@W ; also emits ssrc/sdst via extended cols ----
template <int K, bool BN>
__global__ __launch_bounds__(256) void k_in_gemm(
    const float* __restrict__ in, const float* __restrict__ Wext,
    const float* __restrict__ AB, float* __restrict__ xp,
    float* __restrict__ ssrc, float* __restrict__ sdst) {
  constexpr int KP = (K % 8 == 0) ? K + 4 : K;   // pad stride when K%8==0 (bank spread)
  __shared__ __align__(16) float xs[64 * KP];
  __shared__ __align__(16) float wl[K * 132];
  int t = threadIdx.x;
  int n0 = blockIdx.x * 64;

  for (int u = t; u < K * 33; u += 256) ((float4*)wl)[u] = ((const float4*)Wext)[u];

  constexpr int RQ = K / 4;
  for (int u = t; u < 64 * RQ; u += 256) {
    int r = u / RQ, q = u % RQ;
    int n = n0 + r;
    float4 v = make_float4(0.f, 0.f, 0.f, 0.f);
    if (n < NN) v = ((const float4*)(in + (size_t)n * K))[q];
    if (BN) {
      float4 a4 = ((const float4*)AB)[q];
      float4 b4 = ((const float4*)(AB + 64))[q];
      v.x = v.x * a4.x + b4.x; v.y = v.y * a4.y + b4.y;
      v.z = v.z * a4.z + b4.z; v.w = v.w * a4.w + b4.w;
    }
    ((float4*)(xs + r * KP))[q] = v;
  }
  __syncthreads();

  int ng = t >> 5, cg = t & 31;   // 8 node-groups x 32 col-groups(float4)
  int r0 = ng * 8;
  float4 acc[8];
#pragma unroll
  for (int i = 0; i < 8; ++i) acc[i] = make_float4(0.f, 0.f, 0.f, 0.f);

  for (int k = 0; k < K; ++k) {
    float4 w4 = ((float4*)wl)[k * 33 + cg];
#pragma unroll
    for (int i = 0; i < 8; ++i) {
      float a = xs[(r0 + i) * KP + k];
      acc[i].x += a * w4.x; acc[i].y += a * w4.y;
      acc[i].z += a * w4.z; acc[i].w += a * w4.w;
    }
  }
#pragma unroll
  for (int i = 0; i < 8; ++i) {
    int n = n0 + r0 + i;
    if (n < NN) ((float4*)(xp + (size_t)n * HC))[cg] = acc[i];
  }
  // score columns: 64 rows x 4 scores
  {
    int r = t >> 2, s = t & 3;
    float sc = 0.f;
    for (int k = 0; k < K; ++k) sc += xs[r * KP + k] * wl[k * 132 + 128 + s];
    int n = n0 + r;
    if (n < NN) {
      if (s < 2) ssrc[n * 2 + s] = sc;
      else       sdst[n * 2 + (s - 2)] = sc;
    }
  }
}

// ---- GAT: per-graph edge softmax + aggregation (32 edges + self-loop) ----
__global__ __launch_bounds__(256) void k_gat(
    const float* __restrict__ xp, const float* __restrict__ ssrc,
    const float* __restrict__ sdst, const int* __restrict__ esrc,
    const float* __restrict__ bg, float* __restrict__ out) {
  __shared__ __align__(16) float xl[NPGc * HC];          // 51.2 KB
  __shared__ float ssl[NPGc * 2];
  __shared__ float sdl[NPGc * 2];
  __shared__ unsigned short srcl[NPGc * DEG];            // local src ids
  __shared__ float alpha[NPGc * 2 * (DEG + 2)];          // [d][h][j], j=DEG is self
  int t = threadIdx.x;
  int base = blockIdx.x * NPGc;

  for (int u = t; u < NPGc * (HC / 4); u += 256)
    ((float4*)xl)[u] = ((const float4*)(xp + (size_t)base * HC))[u];
  for (int u = t; u < NPGc * 2; u += 256) {
    ssl[u] = ssrc[base * 2 + u];
    sdl[u] = sdst[base * 2 + u];
  }
  for (int u = t; u < NPGc * DEG; u += 256)
    srcl[u] = (unsigned short)(esrc[base * DEG + u] - base);
  __syncthreads();

  if (t < NPGc * 2) {
    int d = t >> 1, h = t & 1;
    float sd = sdl[d * 2 + h];
    float es = lrelu(ssl[d * 2 + h] + sd);   // self-loop score
    float m = es;
    float e[DEG];
#pragma unroll
    for (int j = 0; j < DEG; ++j) {
      int s = srcl[d * DEG + j];
      e[j] = lrelu(ssl[s * 2 + h] + sd);
      m = fmaxf(m, e[j]);
    }
    float exs = __expf(es - m);
    float den = exs;
#pragma unroll
    for (int j = 0; j < DEG; ++j) { e[j] = __expf(e[j] - m); den += e[j]; }
    float inv = 1.0f / den;
    float* al = alpha + (d * 2 + h) * (DEG + 2);
#pragma unroll
    for (int j = 0; j < DEG; ++j) al[j] = e[j] * inv;
    al[DEG] = exs * inv;
  }
  __syncthreads();

  for (int u = t; u < NPGc * 32; u += 256) {
    int d = u >> 5, c4 = u & 31, h = c4 >> 4;
    const float* al = alpha + (d * 2 + h) * (DEG + 2);
    const unsigned short* sp = srcl + d * DEG;
    float aself = al[DEG];
    float4 x4 = ((float4*)xl)[d * 32 + c4];
    float4 acc;
    acc.x = aself * x4.x; acc.y = aself * x4.y;
    acc.z = aself * x4.z; acc.w = aself * x4.w;
#pragma unroll 8
    for (int j = 0; j < DEG; ++j) {
      float a = al[j];
      float4 v = ((float4*)xl)[(int)sp[j] * 32 + c4];
      acc.x += a * v.x; acc.y += a * v.y;
      acc.z += a * v.z; acc.w += a * v.w;
    }
    float4 bgv = ((const float4*)bg)[c4];
    acc.x += bgv.x; acc.y += bgv.y; acc.z += bgv.z; acc.w += bgv.w;
    ((float4*)(out + (size_t)(base + d) * HC))[c4] = acc;
  }
}

// ---- out-GEMM: h = lrelu(g@lW + lb), per-block channel sum/sumsq partials ----
__global__ __launch_bounds__(256) void k_out_gemm(
    const float* __restrict__ gin, const float* __restrict__ lW,
    const float* __restrict__ lb, float* __restrict__ h,
    float* __restrict__ partial) {
  __shared__ __align__(16) float gl[64 * 132];
  __shared__ __align__(16) float wl[HC * HID];
  __shared__ float psum[2 * HID];
  int t = threadIdx.x;
  int n0 = blockIdx.x * 64;

  for (int u = t; u < 64 * 32; u += 256) {
    int r = u >> 5, q = u & 31;
    int n = n0 + r;
    float4 v = make_float4(0.f, 0.f, 0.f, 0.f);
    if (n < NN) v = ((const float4*)(gin + (size_t)n * HC))[q];
    ((float4*)(gl + r * 132))[q] = v;
  }
  for (int u = t; u < HC * (HID / 4); u += 256)
    ((float4*)wl)[u] = ((const float4*)lW)[u];
  if (t < 2 * HID) psum[t] = 0.f;
  __syncthreads();

  int ng = t >> 4, cg = t & 15;   // 16 node-groups x 16 col-groups(float4)
  int r0 = ng * 4;
  float4 acc[4];
#pragma unroll
  for (int i = 0; i < 4; ++i) acc[i] = make_float4(0.f, 0.f, 0.f, 0.f);

  for (int k = 0; k < HC; ++k) {
    float4 w4 = ((float4*)wl)[k * 16 + cg];
#pragma unroll
    for (int i = 0; i < 4; ++i) {
      float a = gl[(r0 + i) * 132 + k];
      acc[i].x += a * w4.x; acc[i].y += a * w4.y;
      acc[i].z += a * w4.z; acc[i].w += a * w4.w;
    }
  }
  float4 bias = ((const float4*)lb)[cg];
  float s0 = 0, s1 = 0, s2 = 0, s3 = 0, q0 = 0, q1 = 0, q2 = 0, q3 = 0;
#pragma unroll
  for (int i = 0; i < 4; ++i) {
    int n = n0 + r0 + i;
    if (n < NN) {
      float4 v;
      v.x = lrelu(acc[i].x + bias.x); v.y = lrelu(acc[i].y + bias.y);
      v.z = lrelu(acc[i].z + bias.z); v.w = lrelu(acc[i].w + bias.w);
      ((float4*)(h + (size_t)n * HID))[cg] = v;
      s0 += v.x; q0 += v.x * v.x; s1 += v.y; q1 += v.y * v.y;
      s2 += v.z; q2 += v.z * v.z; s3 += v.w; q3 += v.w * v.w;
    }
  }
  int c0 = cg * 4;
  atomicAdd(&psum[c0 + 0], s0); atomicAdd(&psum[c0 + 1], s1);
  atomicAdd(&psum[c0 + 2], s2); atomicAdd(&psum[c0 + 3], s3);
  atomicAdd(&psum[HID + c0 + 0], q0); atomicAdd(&psum[HID + c0 + 1], q1);
  atomicAdd(&psum[HID + c0 + 2], q2); atomicAdd(&psum[HID + c0 + 3], q3);
  __syncthreads();
  if (t < 2 * HID) partial[blockIdx.x * 128 + t] = psum[t];
}

// ---- stats: reduce partials -> BN fold coefficients A,B ----
__global__ __launch_bounds__(256) void k_stats(
    const float* __restrict__ partial, int nb, const float* __restrict__ gamma,
    const float* __restrict__ beta, float* __restrict__ AB) {
  __shared__ float red[2][256];
  int c = blockIdx.x, t = threadIdx.x;
  float s = 0.f, sq = 0.f;
  for (int i = t; i < nb; i += 256) {
    s += partial[i * 128 + c];
    sq += partial[i * 128 + 64 + c];
  }
  red[0][t] = s; red[1][t] = sq;
  __syncthreads();
  for (int o = 128; o > 0; o >>= 1) {
    if (t < o) { red[0][t] += red[0][t + o]; red[1][t] += red[1][t + o]; }
    __syncthreads();
  }
  if (t == 0) {
    float mean = red[0][0] / (float)NN;
    float var = red[1][0] / (float)NN - mean * mean;
    float A = gamma[c] * rsqrtf(var + 1e-5f);
    AB[c] = A;
    AB[64 + c] = beta[c] - mean * A;
  }
}

// ---- pool + MLP head: per-graph mean of BN(h2) -> 64 -> 32 -> 2 ----
__global__ __launch_bounds__(64) void k_pool_mlp(
    const float* __restrict__ h2, const float* __restrict__ AB,
    const float* __restrict__ f1W, const float* __restrict__ f1b,
    const float* __restrict__ f2W, const float* __restrict__ f2b,
    const float* __restrict__ f3W, const float* __restrict__ f3b,
    float* __restrict__ out) {
  __shared__ float pooled[64];
  __shared__ float z1[64];
  __shared__ float z2[32];
  int g = blockIdx.x, t = threadIdx.x;
  const float* hb = h2 + (size_t)g * NPGc * HID;
  float s = 0.f;
  for (int r = 0; r < NPGc; ++r) s += hb[r * HID + t];
  pooled[t] = (s * (1.0f / NPGc)) * AB[t] + AB[64 + t];
  __syncthreads();
  float a = f1b[t];
  for (int c = 0; c < 64; ++c) a += pooled[c] * f1W[c * 64 + t];
  z1[t] = lrelu(a);
  __syncthreads();
  if (t < 32) {
    float a2 = f2b[t];
    for (int c = 0; c < 64; ++c) a2 += z1[c] * f2W[c * 32 + t];
    z2[t] = lrelu(a2);
  }
  __syncthreads();
  if (t < 2) {
    float a3 = f3b[t];
    for (int c = 0; c < 32; ++c) a3 += z2[c] * f3W[c * 2 + t];
    out[g * 2 + t] = a3;
  }
}

extern "C" void kernel_launch(void* const* d_in, const int* in_sizes, int n_in,
                              void* d_out, int out_size, void* d_ws, size_t ws_size,
                              hipStream_t stream) {
  const float* x   = (const float*)d_in[0];
  const float* W1  = (const float*)d_in[2];
  const float* as1 = (const float*)d_in[3];
  const float* ad1 = (const float*)d_in[4];
  const float* bg1 = (const float*)d_in[5];
  const float* l1W = (const float*)d_in[6];
  const float* l1b = (const float*)d_in[7];
  const float* g1  = (const float*)d_in[8];
  const float* b1  = (const float*)d_in[9];
  const float* W2  = (const float*)d_in[10];
  const float* as2 = (const float*)d_in[11];
  const float* ad2 = (const float*)d_in[12];
  const float* bg2 = (const float*)d_in[13];
  const float* l2W = (const float*)d_in[14];
  const float* l2b = (const float*)d_in[15];
  const float* g2  = (const float*)d_in[16];
  const float* b2  = (const float*)d_in[17];
  const float* f1W = (const float*)d_in[18];
  const float* f1b = (const float*)d_in[19];
  const float* f2W = (const float*)d_in[20];
  const float* f2b = (const float*)d_in[21];
  const float* f3W = (const float*)d_in[22];
  const float* f3b = (const float*)d_in[23];
  const int* esrc  = (const int*)d_in[24];   // row 0 of edge_index
  float* out = (float*)d_out;

  float* ws = (float*)d_ws;
  size_t off = 0;
  auto alloc = [&](size_t nf) { float* p = ws + off; off += (nf + 63) & ~(size_t)63; return p; };
  float* Wext1   = alloc(100 * 132);
  float* Wext2   = alloc(64 * 132);
  float* xp      = alloc((size_t)NN * HC);
  float* ssrc    = alloc((size_t)NN * 2);
  float* sdst    = alloc((size_t)NN * 2);
  float* gout    = alloc((size_t)NN * HC);
  float* hbuf    = alloc((size_t)NN * HID);
  const int NB = (NN + 63) / 64;   // 782
  float* partial = alloc((size_t)NB * 128);
  float* AB1     = alloc(128);
  float* AB2     = alloc(128);
  (void)in_sizes; (void)n_in; (void)out_size; (void)ws_size;

  k_prep<<<1, 256, 0, stream>>>(W1, as1, ad1, Wext1, 100);
  k_prep<<<1, 256, 0, stream>>>(W2, as2, ad2, Wext2, 64);
  k_in_gemm<100, false><<<NB, 256, 0, stream>>>(x, Wext1, nullptr, xp, ssrc, sdst);
  k_gat<<<NG, 256, 0, stream>>>(xp, ssrc, sdst, esrc, bg1, gout);
  k_out_gemm<<<NB, 256, 0, stream>>>(gout, l1W, l1b, hbuf, partial);
  k_stats<<<64, 256, 0, stream>>>(partial, NB, g1, b1, AB1);
  k_in_gemm<64, true><<<NB, 256, 0, stream>>>(hbuf, Wext2, AB1, xp, ssrc, sdst);
  k_gat<<<NG, 256, 0, stream>>>(xp, ssrc, sdst, esrc, bg2, gout);
  k_out_gemm<<<NB, 256, 0, stream>>>(gout, l2W, l2b, hbuf, partial);
  k_stats<<<64, 256, 0, stream>>>(partial, NB, g2, b2, AB2);
  k_pool_mlp<<<NG, 64, 0, stream>>>(hbuf, AB2, f1W, f1b, f2W, f2b, f3W, f3b, out);
}

// Round 5
// 320.668 us; speedup vs baseline: 1.0971x; 1.0971x over previous
//
#include <hip/hip_runtime.h>

#define NN 50000
#define NPGc 100
#define NG 500
#define DEG 32
#define HC 128
#define HID 64

__device__ __forceinline__ float lrelu(float x) { return x > 0.0f ? x : 0.2f * x; }

// ---- prep: Wa[K][4] = [ W@as_h0 | W@as_h1 | W@ad_h0 | W@ad_h1 ] for both layers ----
__global__ void k_prep(const float* __restrict__ W1, const float* __restrict__ as1,
                       const float* __restrict__ ad1, float* __restrict__ Wa1,
                       const float* __restrict__ W2, const float* __restrict__ as2,
                       const float* __restrict__ ad2, float* __restrict__ Wa2) {
  const float* W  = blockIdx.x ? W2 : W1;
  const float* as_ = blockIdx.x ? as2 : as1;
  const float* ad_ = blockIdx.x ? ad2 : ad1;
  float* Wa = blockIdx.x ? Wa2 : Wa1;
  int K = blockIdx.x ? 64 : 100;
  int t = threadIdx.x;
  for (int u = t; u < K * 4; u += blockDim.x) {
    int k = u >> 2, s = u & 3;
    const float* a = (s < 2) ? as_ : ad_;
    int h = s & 1;
    float acc = 0.f;
    for (int c = 0; c < 64; ++c) acc += W[k * 128 + h * 64 + c] * a[h * 64 + c];
    Wa[k * 4 + s] = acc;
  }
}

// ---- in-GEMM: xp[N,128] = in(@BN?)@W ; W streamed from global (L1/L2-hot) ----
template <int K, bool BN>
__global__ __launch_bounds__(256) void k_in_gemm(
    const float* __restrict__ in, const float* __restrict__ W,
    const float* __restrict__ Wa, const float* __restrict__ AB,
    float* __restrict__ xp, float* __restrict__ ssrc, float* __restrict__ sdst) {
  constexpr int KP = (K % 8 == 0) ? K + 4 : K;   // pad when K%8==0 (score-pass bank spread)
  __shared__ __align__(16) float xs[64 * KP];
  int t = threadIdx.x;
  int n0 = blockIdx.x * 64;

  constexpr int RQ = K / 4;
  for (int u = t; u < 64 * RQ; u += 256) {
    int r = u / RQ, q = u % RQ;
    int n = n0 + r;
    float4 v = make_float4(0.f, 0.f, 0.f, 0.f);
    if (n < NN) v = ((const float4*)(in + (size_t)n * K))[q];
    if (BN) {
      float4 a4 = ((const float4*)AB)[q];
      float4 b4 = ((const float4*)(AB + 64))[q];
      v.x = v.x * a4.x + b4.x; v.y = v.y * a4.y + b4.y;
      v.z = v.z * a4.z + b4.z; v.w = v.w * a4.w + b4.w;
    }
    ((float4*)(xs + r * KP))[q] = v;
  }
  __syncthreads();

  int ng = t >> 5, cg = t & 31;   // 8 node-groups x 32 col-groups(float4)
  int r0 = ng * 8;
  float4 acc[8];
#pragma unroll
  for (int i = 0; i < 8; ++i) acc[i] = make_float4(0.f, 0.f, 0.f, 0.f);

  const float4* W4 = (const float4*)W;
  float4 w4 = W4[cg];                       // k=0 prefetch
  for (int k = 0; k < K; ++k) {
    float4 wc = w4;
    if (k + 1 < K) w4 = W4[(k + 1) * 32 + cg];
#pragma unroll
    for (int i = 0; i < 8; ++i) {
      float a = xs[(r0 + i) * KP + k];
      acc[i].x += a * wc.x; acc[i].y += a * wc.y;
      acc[i].z += a * wc.z; acc[i].w += a * wc.w;
    }
  }
#pragma unroll
  for (int i = 0; i < 8; ++i) {
    int n = n0 + r0 + i;
    if (n < NN) ((float4*)(xp + (size_t)n * HC))[cg] = acc[i];
  }
  // score columns: 64 rows x 4 scores (Wa is tiny, L1-broadcast)
  {
    int r = t >> 2, s = t & 3;
    float sc = 0.f;
    for (int k = 0; k < K; ++k) sc += xs[r * KP + k] * Wa[k * 4 + s];
    int n = n0 + r;
    if (n < NN) {
      if (s < 2) ssrc[n * 2 + s] = sc;
      else       sdst[n * 2 + (s - 2)] = sc;
    }
  }
}

// ---- GAT: per-(graph,head) block; edge softmax + aggregation from LDS ----
__global__ __launch_bounds__(256) void k_gat(
    const float* __restrict__ xp, const float* __restrict__ ssrc,
    const float* __restrict__ sdst, const int* __restrict__ esrc,
    const float* __restrict__ bg, float* __restrict__ out) {
  __shared__ __align__(16) float xl[NPGc * 64];          // 25.6 KB (this head's cols)
  __shared__ float sh[NPGc];
  __shared__ float sdh[NPGc];
  __shared__ unsigned short srcl[NPGc * DEG];            // 6.4 KB
  __shared__ float alpha[NPGc * (DEG + 2)];              // 13.6 KB
  int t = threadIdx.x;
  int g = blockIdx.x >> 1, h = blockIdx.x & 1;
  int base = g * NPGc;

  const float4* xp4 = (const float4*)(xp + (size_t)base * HC);
  for (int u = t; u < NPGc * 16; u += 256)
    ((float4*)xl)[u] = xp4[(u >> 4) * 32 + h * 16 + (u & 15)];
  if (t < NPGc) {
    sh[t] = ssrc[(base + t) * 2 + h];
    sdh[t] = sdst[(base + t) * 2 + h];
  }
  for (int u = t; u < NPGc * DEG; u += 256)
    srcl[u] = (unsigned short)(esrc[base * DEG + u] - base);
  __syncthreads();

  if (t < NPGc) {
    float sd = sdh[t];
    float es = lrelu(sh[t] + sd);   // self-loop score
    float m = es;
    float e[DEG];
#pragma unroll
    for (int j = 0; j < DEG; ++j) {
      e[j] = lrelu(sh[srcl[t * DEG + j]] + sd);
      m = fmaxf(m, e[j]);
    }
    float exs = __expf(es - m);
    float den = exs;
#pragma unroll
    for (int j = 0; j < DEG; ++j) { e[j] = __expf(e[j] - m); den += e[j]; }
    float inv = 1.0f / den;
    float* al = alpha + t * (DEG + 2);
#pragma unroll
    for (int j = 0; j < DEG; ++j) al[j] = e[j] * inv;
    al[DEG] = exs * inv;
  }
  __syncthreads();

  int c4 = t & 15;                         // loop-invariant (256 % 16 == 0)
  float4 bgv = ((const float4*)bg)[h * 16 + c4];
  for (int d = t >> 4; d < NPGc; d += 16) {
    const float* al = alpha + d * (DEG + 2);
    const unsigned short* sp = srcl + d * DEG;
    float aself = al[DEG];
    float4 x4 = ((float4*)xl)[d * 16 + c4];
    float4 acc;
    acc.x = aself * x4.x; acc.y = aself * x4.y;
    acc.z = aself * x4.z; acc.w = aself * x4.w;
#pragma unroll 8
    for (int j = 0; j < DEG; ++j) {
      float a = al[j];
      float4 v = ((float4*)xl)[(int)sp[j] * 16 + c4];
      acc.x += a * v.x; acc.y += a * v.y;
      acc.z += a * v.z; acc.w += a * v.w;
    }
    acc.x += bgv.x; acc.y += bgv.y; acc.z += bgv.z; acc.w += bgv.w;
    ((float4*)out)[(size_t)(base + d) * 32 + h * 16 + c4] = acc;
  }
}

// ---- out-GEMM: h = lrelu(g@lW + lb); lW streamed (L1-resident 32 KB) ----
__global__ __launch_bounds__(256) void k_out_gemm(
    const float* __restrict__ gin, const float* __restrict__ lW,
    const float* __restrict__ lb, float* __restrict__ h,
    float* __restrict__ partial) {
  __shared__ __align__(16) float gl[64 * 132];           // 33.8 KB
  __shared__ float psum[2 * HID];
  int t = threadIdx.x;
  int n0 = blockIdx.x * 64;

  for (int u = t; u < 64 * 32; u += 256) {
    int r = u >> 5, q = u & 31;
    int n = n0 + r;
    float4 v = make_float4(0.f, 0.f, 0.f, 0.f);
    if (n < NN) v = ((const float4*)(gin + (size_t)n * HC))[q];
    ((float4*)(gl + r * 132))[q] = v;
  }
  if (t < 2 * HID) psum[t] = 0.f;
  __syncthreads();

  int ng = t >> 4, cg = t & 15;   // 16 node-groups x 16 col-groups(float4)
  int r0 = ng * 4;
  float4 acc[4];
#pragma unroll
  for (int i = 0; i < 4; ++i) acc[i] = make_float4(0.f, 0.f, 0.f, 0.f);

  const float4* lW4 = (const float4*)lW;
  float4 w4 = lW4[cg];
  for (int k = 0; k < HC; ++k) {
    float4 wc = w4;
    if (k + 1 < HC) w4 = lW4[(k + 1) * 16 + cg];
#pragma unroll
    for (int i = 0; i < 4; ++i) {
      float a = gl[(r0 + i) * 132 + k];
      acc[i].x += a * wc.x; acc[i].y += a * wc.y;
      acc[i].z += a * wc.z; acc[i].w += a * wc.w;
    }
  }
  float4 bias = ((const float4*)lb)[cg];
  float s0 = 0, s1 = 0, s2 = 0, s3 = 0, q0 = 0, q1 = 0, q2 = 0, q3 = 0;
#pragma unroll
  for (int i = 0; i < 4; ++i) {
    int n = n0 + r0 + i;
    if (n < NN) {
      float4 v;
      v.x = lrelu(acc[i].x + bias.x); v.y = lrelu(acc[i].y + bias.y);
      v.z = lrelu(acc[i].z + bias.z); v.w = lrelu(acc[i].w + bias.w);
      ((float4*)(h + (size_t)n * HID))[cg] = v;
      s0 += v.x; q0 += v.x * v.x; s1 += v.y; q1 += v.y * v.y;
      s2 += v.z; q2 += v.z * v.z; s3 += v.w; q3 += v.w * v.w;
    }
  }
  int c0 = cg * 4;
  atomicAdd(&psum[c0 + 0], s0); atomicAdd(&psum[c0 + 1], s1);
  atomicAdd(&psum[c0 + 2], s2); atomicAdd(&psum[c0 + 3], s3);
  atomicAdd(&psum[HID + c0 + 0], q0); atomicAdd(&psum[HID + c0 + 1], q1);
  atomicAdd(&psum[HID + c0 + 2], q2); atomicAdd(&psum[HID + c0 + 3], q3);
  __syncthreads();
  if (t < 2 * HID) partial[blockIdx.x * 128 + t] = psum[t];
}

// ---- stats: reduce partials -> BN fold coefficients A,B ----
__global__ __launch_bounds__(256) void k_stats(
    const float* __restrict__ partial, int nb, const float* __restrict__ gamma,
    const float* __restrict__ beta, float* __restrict__ AB) {
  __shared__ float red[2][256];
  int c = blockIdx.x, t = threadIdx.x;
  float s = 0.f, sq = 0.f;
  for (int i = t; i < nb; i += 256) {
    s += partial[i * 128 + c];
    sq += partial[i * 128 + 64 + c];
  }
  red[0][t] = s; red[1][t] = sq;
  __syncthreads();
  for (int o = 128; o > 0; o >>= 1) {
    if (t < o) { red[0][t] += red[0][t + o]; red[1][t] += red[1][t + o]; }
    __syncthreads();
  }
  if (t == 0) {
    float mean = red[0][0] / (float)NN;
    float var = red[1][0] / (float)NN - mean * mean;
    float A = gamma[c] * rsqrtf(var + 1e-5f);
    AB[c] = A;
    AB[64 + c] = beta[c] - mean * A;
  }
}

// ---- pool + MLP head: per-graph mean of BN(h2) -> 64 -> 32 -> 2 ----
__global__ __launch_bounds__(64) void k_pool_mlp(
    const float* __restrict__ h2, const float* __restrict__ AB,
    const float* __restrict__ f1W, const float* __restrict__ f1b,
    const float* __restrict__ f2W, const float* __restrict__ f2b,
    const float* __restrict__ f3W, const float* __restrict__ f3b,
    float* __restrict__ out) {
  __shared__ float pp[4 * 64];
  __shared__ float pooled[64];
  __shared__ float z1[64];
  __shared__ float z2[32];
  int g = blockIdx.x, t = threadIdx.x;
  const float4* hb4 = (const float4*)(h2 + (size_t)g * NPGc * HID);
  int rq = t >> 4, c4 = t & 15;
  float4 s4 = make_float4(0.f, 0.f, 0.f, 0.f);
  for (int r = rq; r < NPGc; r += 4) {
    float4 v = hb4[r * 16 + c4];
    s4.x += v.x; s4.y += v.y; s4.z += v.z; s4.w += v.w;
  }
  ((float4*)pp)[rq * 16 + c4] = s4;
  __syncthreads();
  pooled[t] = (pp[t] + pp[64 + t] + pp[128 + t] + pp[192 + t]) * (1.0f / NPGc) * AB[t] + AB[64 + t];
  __syncthreads();
  float a = f1b[t];
  for (int c = 0; c < 64; ++c) a += pooled[c] * f1W[c * 64 + t];
  z1[t] = lrelu(a);
  __syncthreads();
  if (t < 32) {
    float a2 = f2b[t];
    for (int c = 0; c < 64; ++c) a2 += z1[c] * f2W[c * 32 + t];
    z2[t] = lrelu(a2);
  }
  __syncthreads();
  if (t < 2) {
    float a3 = f3b[t];
    for (int c = 0; c < 32; ++c) a3 += z2[c] * f3W[c * 2 + t];
    out[g * 2 + t] = a3;
  }
}

extern "C" void kernel_launch(void* const* d_in, const int* in_sizes, int n_in,
                              void* d_out, int out_size, void* d_ws, size_t ws_size,
                              hipStream_t stream) {
  const float* x   = (const float*)d_in[0];
  const float* W1  = (const float*)d_in[2];
  const float* as1 = (const float*)d_in[3];
  const float* ad1 = (const float*)d_in[4];
  const float* bg1 = (const float*)d_in[5];
  const float* l1W = (const float*)d_in[6];
  const float* l1b = (const float*)d_in[7];
  const float* g1  = (const float*)d_in[8];
  const float* b1  = (const float*)d_in[9];
  const float* W2  = (const float*)d_in[10];
  const float* as2 = (const float*)d_in[11];
  const float* ad2 = (const float*)d_in[12];
  const float* bg2 = (const float*)d_in[13];
  const float* l2W = (const float*)d_in[14];
  const float* l2b = (const float*)d_in[15];
  const float* g2  = (const float*)d_in[16];
  const float* b2  = (const float*)d_in[17];
  const float* f1W = (const float*)d_in[18];
  const float* f1b = (const float*)d_in[19];
  const float* f2W = (const float*)d_in[20];
  const float* f2b = (const float*)d_in[21];
  const float* f3W = (const float*)d_in[22];
  const float* f3b = (const float*)d_in[23];
  const int* esrc  = (const int*)d_in[24];   // row 0 of edge_index
  float* out = (float*)d_out;

  float* ws = (float*)d_ws;
  size_t off = 0;
  auto alloc = [&](size_t nf) { float* p = ws + off; off += (nf + 63) & ~(size_t)63; return p; };
  float* Wa1     = alloc(100 * 4);
  float* Wa2     = alloc(64 * 4);
  float* xp      = alloc((size_t)NN * HC);
  float* ssrc    = alloc((size_t)NN * 2);
  float* sdst    = alloc((size_t)NN * 2);
  float* gout    = alloc((size_t)NN * HC);
  float* hbuf    = alloc((size_t)NN * HID);
  const int NB = (NN + 63) / 64;   // 782
  float* partial = alloc((size_t)NB * 128);
  float* AB1     = alloc(128);
  float* AB2     = alloc(128);
  (void)in_sizes; (void)n_in; (void)out_size; (void)ws_size;

  k_prep<<<2, 256, 0, stream>>>(W1, as1, ad1, Wa1, W2, as2, ad2, Wa2);
  k_in_gemm<100, false><<<NB, 256, 0, stream>>>(x, W1, Wa1, nullptr, xp, ssrc, sdst);
  k_gat<<<NG * 2, 256, 0, stream>>>(xp, ssrc, sdst, esrc, bg1, gout);
  k_out_gemm<<<NB, 256, 0, stream>>>(gout, l1W, l1b, hbuf, partial);
  k_stats<<<64, 256, 0, stream>>>(partial, NB, g1, b1, AB1);
  k_in_gemm<64, true><<<NB, 256, 0, stream>>>(hbuf, W2, Wa2, AB1, xp, ssrc, sdst);
  k_gat<<<NG * 2, 256, 0, stream>>>(xp, ssrc, sdst, esrc, bg2, gout);
  k_out_gemm<<<NB, 256, 0, stream>>>(gout, l2W, l2b, hbuf, partial);
  k_stats<<<64, 256, 0, stream>>>(partial, NB, g2, b2, AB2);
  k_pool_mlp<<<NG, 64, 0, stream>>>(hbuf, AB2, f1W, f1b, f2W, f2b, f3W, f3b, out);
}